// Round 8
// baseline (531.414 us; speedup 1.0000x reference)
//
#include <hip/hip_runtime.h>
#include <hip/hip_bf16.h>

typedef __bf16 bf16x8 __attribute__((ext_vector_type(8)));
typedef __bf16 bf16x4 __attribute__((ext_vector_type(4)));
typedef float f32x4 __attribute__((ext_vector_type(4)));

#define GLOBAL_LOAD_LDS16(gp, lp)                                              \
  __builtin_amdgcn_global_load_lds(                                            \
      (const __attribute__((address_space(1))) void*)(gp),                     \
      (__attribute__((address_space(3))) void*)(lp), 16, 0, 0)

// ---------------------------------------------------------------------------
// Prep kernels (one-time, bandwidth-bound)
// ---------------------------------------------------------------------------
__global__ __launch_bounds__(256) void transpose4_f2b_k(
    const float* __restrict__ s0, const float* __restrict__ s1,
    const float* __restrict__ s2, const float* __restrict__ s3,
    __bf16* __restrict__ dst) {
  __shared__ float tile[32][33];
  const float* srcs[4] = {s0, s1, s2, s3};
  const float* src = srcs[blockIdx.z];
  __bf16* d = dst + ((size_t)blockIdx.z << 20);
  const int bx = blockIdx.x * 32, by = blockIdx.y * 32;
  const int tx = threadIdx.x & 31, ty = threadIdx.x >> 5;
#pragma unroll
  for (int i = 0; i < 32; i += 8)
    tile[ty + i][tx] = src[(size_t)(by + ty + i) * 1024 + bx + tx];
  __syncthreads();
#pragma unroll
  for (int i = 0; i < 32; i += 8)
    d[(size_t)(bx + ty + i) * 1024 + by + tx] = (__bf16)tile[tx][ty + i];
}

__global__ __launch_bounds__(256) void transpose_f2b_k(
    const float* __restrict__ src, __bf16* __restrict__ dst, int R, int C) {
  __shared__ float tile[32][33];
  const int bx = blockIdx.x * 32, by = blockIdx.y * 32;
  const int tx = threadIdx.x & 31, ty = threadIdx.x >> 5;
#pragma unroll
  for (int i = 0; i < 32; i += 8)
    tile[ty + i][tx] = src[(size_t)(by + ty + i) * C + bx + tx];
  __syncthreads();
#pragma unroll
  for (int i = 0; i < 32; i += 8)
    dst[(size_t)(bx + ty + i) * R + by + tx] = (__bf16)tile[tx][ty + i];
}

// batched bf16 transpose: per bh, [1024 s][64 d] -> [64 d][1024 s]
__global__ __launch_bounds__(256) void transpose_v_k(
    const __bf16* __restrict__ src, __bf16* __restrict__ dst) {
  __shared__ __bf16 tile[32][33];
  const int bh = blockIdx.z;
  const int s0 = blockIdx.x * 32, d0 = blockIdx.y * 32;
  const size_t base = (size_t)bh << 16;
  const int tx = threadIdx.x & 31, ty = threadIdx.x >> 5;
#pragma unroll
  for (int i = 0; i < 32; i += 8)
    tile[ty + i][tx] = src[base + (size_t)(s0 + ty + i) * 64 + d0 + tx];
  __syncthreads();
#pragma unroll
  for (int i = 0; i < 32; i += 8)
    dst[base + (size_t)(d0 + ty + i) * 1024 + s0 + tx] = tile[tx][ty + i];
}

__global__ __launch_bounds__(256) void convert_f2b_k(const float* __restrict__ s,
                                                     __bf16* __restrict__ d) {
  const size_t i = ((size_t)blockIdx.x * 256 + threadIdx.x) * 4;
  const float4 v = *(const float4*)(s + i);
  bf16x4 o;
  o[0] = (__bf16)v.x; o[1] = (__bf16)v.y; o[2] = (__bf16)v.z; o[3] = (__bf16)v.w;
  *(bf16x4*)(d + i) = o;
}

__global__ void concat3_k(const float* a, const float* b, const float* c,
                          float* o) {
  int i = blockIdx.x * 256 + threadIdx.x;
  if (i < 1024) o[i] = a[i];
  else if (i < 2048) o[i] = b[i - 1024];
  else if (i < 3072) o[i] = c[i - 2048];
}

// ---------------------------------------------------------------------------
// GEMM (m97): C[M,N] = A @ Bt^T + bias. BM=BN=128, BK=32.
// EPI: 0 = plain, 1 = ReLU, 2 = QKV head-split scatter (N==3072)
// Epilogue: nt innermost so each 128B line gets 4 consecutive 32B stores.
// ---------------------------------------------------------------------------
template <int EPI>
__global__ __launch_bounds__(256) void gemm_bt(const __bf16* __restrict__ A,
                                               const __bf16* __restrict__ Bt,
                                               const float* __restrict__ bias,
                                               __bf16* __restrict__ C,
                                               int M, int N, int K) {
  __shared__ __align__(16) __bf16 As[128 * 32];
  __shared__ __align__(16) __bf16 Bs[128 * 32];
  const int tid = threadIdx.x;
  const int wave = tid >> 6, lane = tid & 63;
  const int quad = lane >> 4, l15 = lane & 15;
  const int wm = wave >> 1, wn = wave & 1;
  const int m0 = blockIdx.x * 128, n0 = blockIdx.y * 128;
  const int rsub = lane >> 2;
  const int kch = lane & 3;

  f32x4 acc[4][4] = {};

  for (int k0 = 0; k0 < K; k0 += 32) {
#pragma unroll
    for (int j = 0; j < 2; ++j) {
      const int rg = (wave * 2 + j) * 16 + rsub;
      GLOBAL_LOAD_LDS16(A + (size_t)(m0 + rg) * K + k0 + kch * 8,
                        As + (wave * 2 + j) * 512);
      GLOBAL_LOAD_LDS16(Bt + (size_t)(n0 + rg) * K + k0 + kch * 8,
                        Bs + (wave * 2 + j) * 512);
    }
    __syncthreads();
    bf16x8 af[4], bfr[4];
#pragma unroll
    for (int mt = 0; mt < 4; ++mt)
      af[mt] = *(const bf16x8*)(As + (wm * 64 + mt * 16 + l15) * 32 + quad * 8);
#pragma unroll
    for (int nt = 0; nt < 4; ++nt)
      bfr[nt] = *(const bf16x8*)(Bs + (wn * 64 + nt * 16 + l15) * 32 + quad * 8);
#pragma unroll
    for (int mt = 0; mt < 4; ++mt)
#pragma unroll
      for (int nt = 0; nt < 4; ++nt)
        acc[mt][nt] = __builtin_amdgcn_mfma_f32_16x16x32_bf16(
            af[mt], bfr[nt], acc[mt][nt], 0, 0, 0);
    __syncthreads();
  }

  float bv[4];
#pragma unroll
  for (int nt = 0; nt < 4; ++nt) bv[nt] = bias[n0 + wn * 64 + nt * 16 + l15];
#pragma unroll
  for (int mt = 0; mt < 4; ++mt) {
#pragma unroll
    for (int r = 0; r < 4; ++r) {
      const int row = m0 + wm * 64 + mt * 16 + quad * 4 + r;
#pragma unroll
      for (int nt = 0; nt < 4; ++nt) {
        const int col = n0 + wn * 64 + nt * 16 + l15;
        float v = acc[mt][nt][r] + bv[nt];
        if (EPI == 1) v = fmaxf(v, 0.0f);
        size_t oidx;
        if (EPI == 2) {
          const int which = col >> 10, wi = col & 1023;
          const int h = wi >> 6, d = wi & 63;
          const int b = row >> 10, s = row & 1023;
          oidx = ((size_t)which << 23) +
                 (((size_t)(b * 16 + h) << 16) + s * 64 + d);
        } else {
          oidx = (size_t)row * N + col;
        }
        C[oidx] = (__bf16)v;
      }
    }
  }
}

// ---------------------------------------------------------------------------
// Narrow-N GEMM for N==1024 shapes (Wo, FFN2): BM=128, BN=64, BK=64.
// XOR chunk swizzle in LDS: LDS[row][c] = G[row][c^(row&7)].
// ---------------------------------------------------------------------------
__global__ __launch_bounds__(256) void gemm_bt64(const __bf16* __restrict__ A,
                                                 const __bf16* __restrict__ Bt,
                                                 const float* __restrict__ bias,
                                                 __bf16* __restrict__ C,
                                                 int M, int N, int K) {
  __shared__ __align__(16) __bf16 As[128 * 64];
  __shared__ __align__(16) __bf16 Bs[64 * 64];
  const int tid = threadIdx.x;
  const int wave = tid >> 6, lane = tid & 63;
  const int quad = lane >> 4, l15 = lane & 15;
  const int wm = wave >> 1, wn = wave & 1;
  const int m0 = blockIdx.x * 128, n0 = blockIdx.y * 64;
  const int srow = tid >> 3;
  const int sch = tid & 7;

  f32x4 acc[4][2] = {};

  for (int k0 = 0; k0 < K; k0 += 64) {
#pragma unroll
    for (int p = 0; p < 4; ++p) {
      const int row = p * 32 + srow;
      GLOBAL_LOAD_LDS16(A + (size_t)(m0 + row) * K + k0 + ((sch ^ (row & 7)) * 8),
                        As + p * 2048 + wave * 512);
    }
#pragma unroll
    for (int p = 0; p < 2; ++p) {
      const int row = p * 32 + srow;
      GLOBAL_LOAD_LDS16(Bt + (size_t)(n0 + row) * K + k0 + ((sch ^ (row & 7)) * 8),
                        Bs + p * 2048 + wave * 512);
    }
    __syncthreads();
    bf16x8 af[4][2], bfr[2][2];
#pragma unroll
    for (int kk = 0; kk < 2; ++kk) {
#pragma unroll
      for (int mt = 0; mt < 4; ++mt) {
        const int row = wm * 64 + mt * 16 + l15;
        af[mt][kk] =
            *(const bf16x8*)(As + row * 64 + (((kk * 4 + quad) ^ (row & 7)) * 8));
      }
#pragma unroll
      for (int nt = 0; nt < 2; ++nt) {
        const int row = wn * 32 + nt * 16 + l15;
        bfr[nt][kk] =
            *(const bf16x8*)(Bs + row * 64 + (((kk * 4 + quad) ^ (row & 7)) * 8));
      }
    }
#pragma unroll
    for (int kk = 0; kk < 2; ++kk)
#pragma unroll
      for (int mt = 0; mt < 4; ++mt)
#pragma unroll
        for (int nt = 0; nt < 2; ++nt)
          acc[mt][nt] = __builtin_amdgcn_mfma_f32_16x16x32_bf16(
              af[mt][kk], bfr[nt][kk], acc[mt][nt], 0, 0, 0);
    __syncthreads();
  }

  float bv[2];
#pragma unroll
  for (int nt = 0; nt < 2; ++nt) bv[nt] = bias[n0 + wn * 32 + nt * 16 + l15];
#pragma unroll
  for (int mt = 0; mt < 4; ++mt) {
#pragma unroll
    for (int r = 0; r < 4; ++r) {
      const int row = m0 + wm * 64 + mt * 16 + quad * 4 + r;
#pragma unroll
      for (int nt = 0; nt < 2; ++nt) {
        const int col = n0 + wn * 32 + nt * 16 + l15;
        C[(size_t)row * N + col] = (__bf16)(acc[mt][nt][r] + bv[nt]);
      }
    }
  }
}

// ---------------------------------------------------------------------------
// Flash attention, causal strict (key < query), query row 0 zeroed per (b,h).
// No-max softmax; balanced q-tile pairs (a, 7-a): 18 key-tiles per block.
// 512 threads / 8 waves; each wave owns 16 q-rows of the 128-row tile.
// grid (4, 128). Q,K: [bh][1024][64]; Vt: [bh][64][1024].
// ---------------------------------------------------------------------------
__global__ __launch_bounds__(512) void attn_kernel(const __bf16* __restrict__ Q,
                                                   const __bf16* __restrict__ Kg,
                                                   const __bf16* __restrict__ Vt,
                                                   __bf16* __restrict__ ctx) {
  const int qp = blockIdx.x;   // 0..3
  const int bh = blockIdx.y;   // 0..127
  const int b = bh >> 4, h = bh & 15;
  const int tid = threadIdx.x, wave = tid >> 6, lane = tid & 63;
  const int quad = lane >> 4, l15 = lane & 15;
  const size_t hoff = (size_t)bh << 16;
  const __bf16* Qh = Q + hoff;
  const __bf16* Kh = Kg + hoff;
  const __bf16* Vh = Vt + hoff;

  __shared__ __align__(16) __bf16 Ks[64 * 64];    // [key][chunk^(key&7)]
  __shared__ __align__(16) __bf16 Vs[64 * 64];    // [d][chunk^(d&7)]
  __shared__ __align__(16) __bf16 Ps[8][16 * 72]; // per-wave P [q][key]
  __shared__ float lL[128];

  // staging: wave w stages rows [w*8, w*8+8) of K and of Vt (1 DMA each)
  const int srow = wave * 8 + (lane >> 3);
  const int sgr = lane & 7;

#pragma unroll
  for (int pass = 0; pass < 2; ++pass) {
    const int qt = pass ? (7 - qp) : qp;
    const int qb = qt * 128;

    // Q fragments (A-layout), pre-scaled by 1/sqrt(d)=0.125 (exact in bf16)
    bf16x8 qf[2];
    {
      const int qrow = qb + wave * 16 + l15;
      bf16x8 t0 = *(const bf16x8*)(Qh + (size_t)qrow * 64 + quad * 8);
      bf16x8 t1 = *(const bf16x8*)(Qh + (size_t)qrow * 64 + 32 + quad * 8);
#pragma unroll
      for (int e = 0; e < 8; ++e) {
        qf[0][e] = (__bf16)((float)t0[e] * 0.125f);
        qf[1][e] = (__bf16)((float)t1[e] * 0.125f);
      }
    }

    f32x4 oacc[4] = {};   // O^T: d = mdt*16+quad*4+r, q = l15
    float lrun[4] = {};   // per-lane partial denominators (q = quad*4+r)

    const int ktmax = 2 * qt + 1;
    for (int kt = 0; kt <= ktmax; ++kt) {
      __syncthreads();
      GLOBAL_LOAD_LDS16(
          Kh + (size_t)(kt * 64 + srow) * 64 + ((sgr ^ (srow & 7)) * 8),
          Ks + wave * 512);
      GLOBAL_LOAD_LDS16(
          Vh + (size_t)srow * 1024 + kt * 64 + ((sgr ^ (srow & 7)) * 8),
          Vs + wave * 512);
      __syncthreads();

      // ---- S = Q K^T : wave tile [16 q][64 key] ----
      f32x4 sacc[4] = {};
#pragma unroll
      for (int nt = 0; nt < 4; ++nt) {
        const int key = nt * 16 + l15, sw = key & 7;
        bf16x8 kf0 = *(const bf16x8*)(Ks + key * 64 + ((quad ^ sw) * 8));
        bf16x8 kf1 = *(const bf16x8*)(Ks + key * 64 + (((quad + 4) ^ sw) * 8));
        sacc[nt] = __builtin_amdgcn_mfma_f32_16x16x32_bf16(qf[0], kf0,
                                                           sacc[nt], 0, 0, 0);
        sacc[nt] = __builtin_amdgcn_mfma_f32_16x16x32_bf16(qf[1], kf1,
                                                           sacc[nt], 0, 0, 0);
      }

      // ---- p = exp(s) (clamped), mask -> 0, accumulate partial sums ----
      const bool tilemask = (kt * 64 + 63 >= qb + wave * 16);
#pragma unroll
      for (int nt = 0; nt < 4; ++nt) {
        const int key = kt * 64 + nt * 16 + l15;
#pragma unroll
        for (int r = 0; r < 4; ++r) {
          float p = __expf(fminf(sacc[nt][r], 60.0f));
          if (tilemask && key >= qb + wave * 16 + quad * 4 + r) p = 0.0f;
          sacc[nt][r] = p;
          lrun[r] += p;
        }
      }

      // ---- write P (bf16) to per-wave LDS (no block barrier needed) ----
#pragma unroll
      for (int nt = 0; nt < 4; ++nt)
#pragma unroll
        for (int r = 0; r < 4; ++r)
          Ps[wave][(quad * 4 + r) * 72 + nt * 16 + l15] = (__bf16)sacc[nt][r];

      // ---- O^T += V^T P^T ----
#pragma unroll
      for (int kc = 0; kc < 2; ++kc) {
        bf16x8 pf =
            *(const bf16x8*)(&Ps[wave][l15 * 72 + kc * 32 + quad * 8]);
#pragma unroll
        for (int mdt = 0; mdt < 4; ++mdt) {
          const int d = mdt * 16 + l15, sw = d & 7;
          bf16x8 vf =
              *(const bf16x8*)(Vs + d * 64 + (((kc * 4 + quad) ^ sw) * 8));
          oacc[mdt] = __builtin_amdgcn_mfma_f32_16x16x32_bf16(vf, pf,
                                                              oacc[mdt], 0, 0, 0);
        }
      }
    }

    // ---- finalize: reduce l across lanes, /l, zero row 0, store ----
#pragma unroll
    for (int r = 0; r < 4; ++r) {
      float s = lrun[r];
#pragma unroll
      for (int d = 1; d < 16; d <<= 1) s += __shfl_xor(s, d);
      if (l15 == 0) lL[wave * 16 + quad * 4 + r] = s;
    }
    const float l = lL[wave * 16 + l15];
    const float linv = (qb + wave * 16 + l15 == 0) ? 0.0f : (1.0f / l);

    __bf16* Ot = Ps[wave];  // reuse, 16 rows x 72
#pragma unroll
    for (int mdt = 0; mdt < 4; ++mdt)
#pragma unroll
      for (int r = 0; r < 4; ++r)
        Ot[l15 * 72 + mdt * 16 + quad * 4 + r] = (__bf16)(oacc[mdt][r] * linv);
#pragma unroll
    for (int j = 0; j < 2; ++j) {
      const int row = lane >> 2, chk = (lane & 3) + 4 * j;
      bf16x8 ov = *(const bf16x8*)(Ot + row * 72 + chk * 8);
      const size_t oi = ((size_t)(b * 1024 + qb + wave * 16 + row)) * 1024 +
                        h * 64 + chk * 8;
      *(bf16x8*)(ctx + oi) = ov;
    }
  }
}

// ---------------------------------------------------------------------------
// out = LayerNorm(x + y) * g + beta ; rows of 1024, one block per row.
// ---------------------------------------------------------------------------
template <typename TX, typename TY, typename TO>
__global__ __launch_bounds__(256) void add_ln_kernel(const TX* __restrict__ x,
                                                     const TY* __restrict__ y,
                                                     const float* __restrict__ g,
                                                     const float* __restrict__ be,
                                                     TO* __restrict__ out) {
  const int row = blockIdx.x;
  const size_t base = (size_t)row * 1024;
  const int t = threadIdx.x;
  float xv[4], yv[4];
  if constexpr (sizeof(TX) == 4) {
    const float4 a = *(const float4*)(x + base + t * 4);
    xv[0] = a.x; xv[1] = a.y; xv[2] = a.z; xv[3] = a.w;
  } else {
    const bf16x4 a = *(const bf16x4*)(x + base + t * 4);
#pragma unroll
    for (int i = 0; i < 4; ++i) xv[i] = (float)a[i];
  }
  if constexpr (sizeof(TY) == 4) {
    const float4 a = *(const float4*)(y + base + t * 4);
    yv[0] = a.x; yv[1] = a.y; yv[2] = a.z; yv[3] = a.w;
  } else {
    const bf16x4 a = *(const bf16x4*)(y + base + t * 4);
#pragma unroll
    for (int i = 0; i < 4; ++i) yv[i] = (float)a[i];
  }
  float v[4], s = 0.0f, s2 = 0.0f;
#pragma unroll
  for (int i = 0; i < 4; ++i) {
    v[i] = xv[i] + yv[i];
    s += v[i];
    s2 += v[i] * v[i];
  }
#pragma unroll
  for (int m = 1; m < 64; m <<= 1) {
    s += __shfl_xor(s, m);
    s2 += __shfl_xor(s2, m);
  }
  __shared__ float ss[4], ss2[4];
  const int w = t >> 6;
  if ((t & 63) == 0) { ss[w] = s; ss2[w] = s2; }
  __syncthreads();
  s = ss[0] + ss[1] + ss[2] + ss[3];
  s2 = ss2[0] + ss2[1] + ss2[2] + ss2[3];
  const float mu = s * (1.0f / 1024.0f);
  const float var = s2 * (1.0f / 1024.0f) - mu * mu;
  const float rstd = rsqrtf(var + 1e-5f);
#pragma unroll
  for (int i = 0; i < 4; ++i) {
    const float o = (v[i] - mu) * rstd * g[t * 4 + i] + be[t * 4 + i];
    out[base + t * 4 + i] = (TO)o;
  }
}

// ---------------------------------------------------------------------------
extern "C" void kernel_launch(void* const* d_in, const int* in_sizes, int n_in,
                              void* d_out, int out_size, void* d_ws,
                              size_t ws_size, hipStream_t stream) {
  (void)in_sizes; (void)n_in; (void)out_size; (void)ws_size;
  const float* x   = (const float*)d_in[0];
  const float* Wq  = (const float*)d_in[1];
  const float* bq  = (const float*)d_in[2];
  const float* Wk  = (const float*)d_in[3];
  const float* bk  = (const float*)d_in[4];
  const float* Wv  = (const float*)d_in[5];
  const float* bv  = (const float*)d_in[6];
  const float* Wo  = (const float*)d_in[7];
  const float* bo  = (const float*)d_in[8];
  const float* W1  = (const float*)d_in[9];
  const float* b1  = (const float*)d_in[10];
  const float* W2  = (const float*)d_in[11];
  const float* b2  = (const float*)d_in[12];
  const float* g1  = (const float*)d_in[13];
  const float* be1 = (const float*)d_in[14];
  const float* g3  = (const float*)d_in[15];
  const float* be3 = (const float*)d_in[16];

  char* ws = (char*)d_ws;
  __bf16* Qb    = (__bf16*)(ws + 0);
  __bf16* Kb    = (__bf16*)(ws + (16u << 20));
  __bf16* Vb    = (__bf16*)(ws + (32u << 20));
  __bf16* ctx   = (__bf16*)(ws + (48u << 20));
  __bf16* mid   = (__bf16*)(ws + 0);
  __bf16* aout  = (__bf16*)(ws + (64u << 20));
  __bf16* h1    = aout;
  __bf16* xb    = (__bf16*)(ws + (80u << 20));
  __bf16* Vtb   = (__bf16*)(ws + (80u << 20));
  __bf16* fout  = (__bf16*)(ws + (80u << 20));
  __bf16* WqkvT = (__bf16*)(ws + (96u << 20));
  __bf16* WoT   = (__bf16*)(ws + (96u << 20) + 3 * (1u << 21));
  __bf16* W1T   = (__bf16*)(ws + (104u << 20));
  __bf16* W2T   = (__bf16*)(ws + (112u << 20));
  float*  bqkv  = (float*)(ws + (120u << 20));
  float*  outp  = (float*)d_out;

  const dim3 blk(256);
  // ---- prep
  convert_f2b_k<<<dim3(8192), blk, 0, stream>>>(x, xb);
  transpose4_f2b_k<<<dim3(32, 32, 4), blk, 0, stream>>>(Wq, Wk, Wv, Wo, WqkvT);
  transpose_f2b_k<<<dim3(128, 32), blk, 0, stream>>>(W1, W1T, 1024, 4096);
  transpose_f2b_k<<<dim3(32, 128), blk, 0, stream>>>(W2, W2T, 4096, 1024);
  concat3_k<<<dim3(12), blk, 0, stream>>>(bq, bk, bv, bqkv);

  // ---- QKV fused projection (head-split scatter)
  gemm_bt<2><<<dim3(64, 24), blk, 0, stream>>>(xb, WqkvT, bqkv, Qb, 8192, 3072, 1024);
  // ---- V -> V^T per (b,h)
  transpose_v_k<<<dim3(32, 2, 128), blk, 0, stream>>>(Vb, Vtb);
  // ---- attention (balanced pairs, 8 waves/block)
  attn_kernel<<<dim3(4, 128), dim3(512), 0, stream>>>(Qb, Kb, Vtb, ctx);
  // ---- output projection
  gemm_bt64<<<dim3(64, 16), blk, 0, stream>>>(ctx, WoT, bo, aout, 8192, 1024, 1024);
  // ---- h1 = LN(x + attn_out)
  add_ln_kernel<float, __bf16, __bf16><<<dim3(8192), blk, 0, stream>>>(
      x, aout, g1, be1, h1);
  // ---- FFN
  gemm_bt<1><<<dim3(64, 32), blk, 0, stream>>>(h1, W1T, b1, mid, 8192, 4096, 1024);
  gemm_bt64<<<dim3(64, 16), blk, 0, stream>>>(mid, W2T, b2, fout, 8192, 1024, 4096);
  // ---- out = LN(h1 + ffn)
  add_ln_kernel<__bf16, __bf16, float><<<dim3(8192), blk, 0, stream>>>(
      h1, fout, g3, be3, outp);
}

// Round 9
// 481.893 us; speedup vs baseline: 1.1028x; 1.1028x over previous
//
#include <hip/hip_runtime.h>
#include <hip/hip_bf16.h>

typedef __bf16 bf16x8 __attribute__((ext_vector_type(8)));
typedef __bf16 bf16x4 __attribute__((ext_vector_type(4)));
typedef float f32x4 __attribute__((ext_vector_type(4)));
typedef float f32x16 __attribute__((ext_vector_type(16)));

#define GLOBAL_LOAD_LDS16(gp, lp)                                              \
  __builtin_amdgcn_global_load_lds(                                            \
      (const __attribute__((address_space(1))) void*)(gp),                     \
      (__attribute__((address_space(3))) void*)(lp), 16, 0, 0)

// ---------------------------------------------------------------------------
// Prep kernels (one-time, bandwidth-bound)
// ---------------------------------------------------------------------------
__global__ __launch_bounds__(256) void transpose4_f2b_k(
    const float* __restrict__ s0, const float* __restrict__ s1,
    const float* __restrict__ s2, const float* __restrict__ s3,
    __bf16* __restrict__ dst) {
  __shared__ float tile[32][33];
  const float* srcs[4] = {s0, s1, s2, s3};
  const float* src = srcs[blockIdx.z];
  __bf16* d = dst + ((size_t)blockIdx.z << 20);
  const int bx = blockIdx.x * 32, by = blockIdx.y * 32;
  const int tx = threadIdx.x & 31, ty = threadIdx.x >> 5;
#pragma unroll
  for (int i = 0; i < 32; i += 8)
    tile[ty + i][tx] = src[(size_t)(by + ty + i) * 1024 + bx + tx];
  __syncthreads();
#pragma unroll
  for (int i = 0; i < 32; i += 8)
    d[(size_t)(bx + ty + i) * 1024 + by + tx] = (__bf16)tile[tx][ty + i];
}

__global__ __launch_bounds__(256) void transpose_f2b_k(
    const float* __restrict__ src, __bf16* __restrict__ dst, int R, int C) {
  __shared__ float tile[32][33];
  const int bx = blockIdx.x * 32, by = blockIdx.y * 32;
  const int tx = threadIdx.x & 31, ty = threadIdx.x >> 5;
#pragma unroll
  for (int i = 0; i < 32; i += 8)
    tile[ty + i][tx] = src[(size_t)(by + ty + i) * C + bx + tx];
  __syncthreads();
#pragma unroll
  for (int i = 0; i < 32; i += 8)
    dst[(size_t)(bx + ty + i) * R + by + tx] = (__bf16)tile[tx][ty + i];
}

// batched bf16 transpose: per bh, [1024 s][64 d] -> [64 d][1024 s]
__global__ __launch_bounds__(256) void transpose_v_k(
    const __bf16* __restrict__ src, __bf16* __restrict__ dst) {
  __shared__ __bf16 tile[32][33];
  const int bh = blockIdx.z;
  const int s0 = blockIdx.x * 32, d0 = blockIdx.y * 32;
  const size_t base = (size_t)bh << 16;
  const int tx = threadIdx.x & 31, ty = threadIdx.x >> 5;
#pragma unroll
  for (int i = 0; i < 32; i += 8)
    tile[ty + i][tx] = src[base + (size_t)(s0 + ty + i) * 64 + d0 + tx];
  __syncthreads();
#pragma unroll
  for (int i = 0; i < 32; i += 8)
    dst[base + (size_t)(d0 + ty + i) * 1024 + s0 + tx] = tile[tx][ty + i];
}

__global__ __launch_bounds__(256) void convert_f2b_k(const float* __restrict__ s,
                                                     __bf16* __restrict__ d) {
  const size_t i = ((size_t)blockIdx.x * 256 + threadIdx.x) * 4;
  const float4 v = *(const float4*)(s + i);
  bf16x4 o;
  o[0] = (__bf16)v.x; o[1] = (__bf16)v.y; o[2] = (__bf16)v.z; o[3] = (__bf16)v.w;
  *(bf16x4*)(d + i) = o;
}

__global__ void concat3_k(const float* a, const float* b, const float* c,
                          float* o) {
  int i = blockIdx.x * 256 + threadIdx.x;
  if (i < 1024) o[i] = a[i];
  else if (i < 2048) o[i] = b[i - 1024];
  else if (i < 3072) o[i] = c[i - 2048];
}

// ---------------------------------------------------------------------------
// GEMM v2: C[M,N] = A @ Bt^T + bias. BM=BN=128, BK=64, 32x32x16 MFMA.
// Wave tile 64x64 = 2x2 tiles of 32x32. LDS [row][64] with XOR chunk swizzle.
// EPI: 0 = plain, 1 = ReLU, 2 = QKV head-split scatter (N==3072)
// ---------------------------------------------------------------------------
template <int EPI>
__global__ __launch_bounds__(256) void gemm_bt32(const __bf16* __restrict__ A,
                                                 const __bf16* __restrict__ Bt,
                                                 const float* __restrict__ bias,
                                                 __bf16* __restrict__ C,
                                                 int M, int N, int K) {
  __shared__ __align__(16) __bf16 As[128 * 64];
  __shared__ __align__(16) __bf16 Bs[128 * 64];
  const int tid = threadIdx.x;
  const int wave = tid >> 6, lane = tid & 63;
  const int l31 = lane & 31, hi = lane >> 5;
  const int wm = wave >> 1, wn = wave & 1;
  const int m0 = blockIdx.x * 128, n0 = blockIdx.y * 128;
  const int srsub = lane >> 3;  // 0..7 row within 8-row DMA group
  const int sch = lane & 7;     // source 16B chunk

  f32x16 acc[2][2] = {};

  for (int k0 = 0; k0 < K; k0 += 64) {
    // stage A and B tiles [128][64], 4 DMAs each per wave, XOR chunk swizzle
#pragma unroll
    for (int p = 0; p < 4; ++p) {
      const int g = wave * 4 + p;        // 8-row group 0..15
      const int row = g * 8 + srsub;
      GLOBAL_LOAD_LDS16(A + (size_t)(m0 + row) * K + k0 + ((sch ^ (row & 7)) * 8),
                        As + g * 512);
      GLOBAL_LOAD_LDS16(Bt + (size_t)(n0 + row) * K + k0 + ((sch ^ (row & 7)) * 8),
                        Bs + g * 512);
    }
    __syncthreads();
#pragma unroll
    for (int kk = 0; kk < 4; ++kk) {
      bf16x8 af[2], bf[2];
#pragma unroll
      for (int mt = 0; mt < 2; ++mt) {
        const int row = wm * 64 + mt * 32 + l31;
        af[mt] = *(const bf16x8*)(As + row * 64 +
                                  (((kk * 2 + hi) ^ (row & 7)) * 8));
      }
#pragma unroll
      for (int nt = 0; nt < 2; ++nt) {
        const int row = wn * 64 + nt * 32 + l31;
        bf[nt] = *(const bf16x8*)(Bs + row * 64 +
                                  (((kk * 2 + hi) ^ (row & 7)) * 8));
      }
#pragma unroll
      for (int mt = 0; mt < 2; ++mt)
#pragma unroll
        for (int nt = 0; nt < 2; ++nt)
          acc[mt][nt] = __builtin_amdgcn_mfma_f32_32x32x16_bf16(
              af[mt], bf[nt], acc[mt][nt], 0, 0, 0);
    }
    __syncthreads();
  }

  // epilogue: 32x32 C/D layout col=lane&31, row=(i&3)+8*(i>>2)+4*(lane>>5)
  float bvv[2];
#pragma unroll
  for (int nt = 0; nt < 2; ++nt) bvv[nt] = bias[n0 + wn * 64 + nt * 32 + l31];
#pragma unroll
  for (int mt = 0; mt < 2; ++mt) {
#pragma unroll
    for (int i = 0; i < 16; ++i) {
      const int row = m0 + wm * 64 + mt * 32 + (i & 3) + 8 * (i >> 2) + 4 * hi;
#pragma unroll
      for (int nt = 0; nt < 2; ++nt) {
        const int col = n0 + wn * 64 + nt * 32 + l31;
        float v = acc[mt][nt][i] + bvv[nt];
        if (EPI == 1) v = fmaxf(v, 0.0f);
        size_t oidx;
        if (EPI == 2) {
          const int which = col >> 10, wi = col & 1023;
          const int h = wi >> 6, d = wi & 63;
          const int b = row >> 10, s = row & 1023;
          oidx = ((size_t)which << 23) +
                 (((size_t)(b * 16 + h) << 16) + s * 64 + d);
        } else {
          oidx = (size_t)row * N + col;
        }
        C[oidx] = (__bf16)v;
      }
    }
  }
}

// ---------------------------------------------------------------------------
// Narrow-N GEMM for N==1024 shapes (Wo, FFN2): BM=128, BN=64, BK=64.
// XOR chunk swizzle in LDS: LDS[row][c] = G[row][c^(row&7)].
// ---------------------------------------------------------------------------
__global__ __launch_bounds__(256) void gemm_bt64(const __bf16* __restrict__ A,
                                                 const __bf16* __restrict__ Bt,
                                                 const float* __restrict__ bias,
                                                 __bf16* __restrict__ C,
                                                 int M, int N, int K) {
  __shared__ __align__(16) __bf16 As[128 * 64];
  __shared__ __align__(16) __bf16 Bs[64 * 64];
  const int tid = threadIdx.x;
  const int wave = tid >> 6, lane = tid & 63;
  const int quad = lane >> 4, l15 = lane & 15;
  const int wm = wave >> 1, wn = wave & 1;
  const int m0 = blockIdx.x * 128, n0 = blockIdx.y * 64;
  const int srow = tid >> 3;
  const int sch = tid & 7;

  f32x4 acc[4][2] = {};

  for (int k0 = 0; k0 < K; k0 += 64) {
#pragma unroll
    for (int p = 0; p < 4; ++p) {
      const int row = p * 32 + srow;
      GLOBAL_LOAD_LDS16(A + (size_t)(m0 + row) * K + k0 + ((sch ^ (row & 7)) * 8),
                        As + p * 2048 + wave * 512);
    }
#pragma unroll
    for (int p = 0; p < 2; ++p) {
      const int row = p * 32 + srow;
      GLOBAL_LOAD_LDS16(Bt + (size_t)(n0 + row) * K + k0 + ((sch ^ (row & 7)) * 8),
                        Bs + p * 2048 + wave * 512);
    }
    __syncthreads();
    bf16x8 af[4][2], bfr[2][2];
#pragma unroll
    for (int kk = 0; kk < 2; ++kk) {
#pragma unroll
      for (int mt = 0; mt < 4; ++mt) {
        const int row = wm * 64 + mt * 16 + l15;
        af[mt][kk] =
            *(const bf16x8*)(As + row * 64 + (((kk * 4 + quad) ^ (row & 7)) * 8));
      }
#pragma unroll
      for (int nt = 0; nt < 2; ++nt) {
        const int row = wn * 32 + nt * 16 + l15;
        bfr[nt][kk] =
            *(const bf16x8*)(Bs + row * 64 + (((kk * 4 + quad) ^ (row & 7)) * 8));
      }
    }
#pragma unroll
    for (int kk = 0; kk < 2; ++kk)
#pragma unroll
      for (int mt = 0; mt < 4; ++mt)
#pragma unroll
        for (int nt = 0; nt < 2; ++nt)
          acc[mt][nt] = __builtin_amdgcn_mfma_f32_16x16x32_bf16(
              af[mt][kk], bfr[nt][kk], acc[mt][nt], 0, 0, 0);
    __syncthreads();
  }

  float bv[2];
#pragma unroll
  for (int nt = 0; nt < 2; ++nt) bv[nt] = bias[n0 + wn * 32 + nt * 16 + l15];
#pragma unroll
  for (int mt = 0; mt < 4; ++mt) {
#pragma unroll
    for (int r = 0; r < 4; ++r) {
      const int row = m0 + wm * 64 + mt * 16 + quad * 4 + r;
#pragma unroll
      for (int nt = 0; nt < 2; ++nt) {
        const int col = n0 + wn * 32 + nt * 16 + l15;
        C[(size_t)row * N + col] = (__bf16)(acc[mt][nt][r] + bv[nt]);
      }
    }
  }
}

// ---------------------------------------------------------------------------
// Flash attention (round-7 measured config): causal strict, row 0 zeroed.
// No-max softmax; balanced q-tile pairs (a, 7-a): 18 key-tiles per block.
// grid (4, 128), 256 threads / 4 waves; wave owns 32 q rows.
// ---------------------------------------------------------------------------
__global__ __launch_bounds__(256) void attn_kernel(const __bf16* __restrict__ Q,
                                                   const __bf16* __restrict__ Kg,
                                                   const __bf16* __restrict__ Vt,
                                                   __bf16* __restrict__ ctx) {
  const int qp = blockIdx.x;   // 0..3
  const int bh = blockIdx.y;   // 0..127
  const int b = bh >> 4, h = bh & 15;
  const int tid = threadIdx.x, wave = tid >> 6, lane = tid & 63;
  const int quad = lane >> 4, l15 = lane & 15;
  const size_t hoff = (size_t)bh << 16;
  const __bf16* Qh = Q + hoff;
  const __bf16* Kh = Kg + hoff;
  const __bf16* Vh = Vt + hoff;

  __shared__ __align__(16) __bf16 Ks[64 * 64];
  __shared__ __align__(16) __bf16 Vs[64 * 64];
  __shared__ __align__(16) __bf16 Ps[4][32 * 72];
  __shared__ float lL[128];

  const int skey = wave * 8 + (lane >> 3);
  const int sgr = lane & 7;

#pragma unroll
  for (int pass = 0; pass < 2; ++pass) {
    const int qt = pass ? (7 - qp) : qp;
    const int qb = qt * 128;

    bf16x8 qf[2][2];
#pragma unroll
    for (int g = 0; g < 2; ++g) {
      const int qrow = qb + wave * 32 + g * 16 + l15;
      bf16x8 t0 = *(const bf16x8*)(Qh + (size_t)qrow * 64 + quad * 8);
      bf16x8 t1 = *(const bf16x8*)(Qh + (size_t)qrow * 64 + 32 + quad * 8);
#pragma unroll
      for (int e = 0; e < 8; ++e) {
        qf[g][0][e] = (__bf16)((float)t0[e] * 0.125f);
        qf[g][1][e] = (__bf16)((float)t1[e] * 0.125f);
      }
    }

    f32x4 oacc[4][2] = {};
    float lrun[2][4] = {};

    const int ktmax = 2 * qt + 1;
    for (int kt = 0; kt <= ktmax; ++kt) {
      __syncthreads();
#pragma unroll
      for (int j = 0; j < 2; ++j) {
        const int row = skey + 32 * j;
        GLOBAL_LOAD_LDS16(
            Kh + (size_t)(kt * 64 + row) * 64 + ((sgr ^ (row & 7)) * 8),
            Ks + j * 2048 + wave * 512);
        GLOBAL_LOAD_LDS16(
            Vh + (size_t)row * 1024 + kt * 64 + ((sgr ^ (row & 7)) * 8),
            Vs + j * 2048 + wave * 512);
      }
      __syncthreads();

      f32x4 sacc[2][4] = {};
#pragma unroll
      for (int nt = 0; nt < 4; ++nt) {
        const int key = nt * 16 + l15, sw = key & 7;
        bf16x8 kf0 = *(const bf16x8*)(Ks + key * 64 + ((quad ^ sw) * 8));
        bf16x8 kf1 = *(const bf16x8*)(Ks + key * 64 + (((quad + 4) ^ sw) * 8));
#pragma unroll
        for (int g = 0; g < 2; ++g) {
          sacc[g][nt] = __builtin_amdgcn_mfma_f32_16x16x32_bf16(
              qf[g][0], kf0, sacc[g][nt], 0, 0, 0);
          sacc[g][nt] = __builtin_amdgcn_mfma_f32_16x16x32_bf16(
              qf[g][1], kf1, sacc[g][nt], 0, 0, 0);
        }
      }

      const bool tilemask = (kt >= 2 * qt);
#pragma unroll
      for (int g = 0; g < 2; ++g)
#pragma unroll
        for (int nt = 0; nt < 4; ++nt) {
          const int key = kt * 64 + nt * 16 + l15;
#pragma unroll
          for (int r = 0; r < 4; ++r) {
            float p = __expf(fminf(sacc[g][nt][r], 60.0f));
            if (tilemask && key >= qb + wave * 32 + g * 16 + quad * 4 + r)
              p = 0.0f;
            sacc[g][nt][r] = p;
            lrun[g][r] += p;
          }
        }

#pragma unroll
      for (int g = 0; g < 2; ++g)
#pragma unroll
        for (int nt = 0; nt < 4; ++nt)
#pragma unroll
          for (int r = 0; r < 4; ++r)
            Ps[wave][(g * 16 + quad * 4 + r) * 72 + nt * 16 + l15] =
                (__bf16)sacc[g][nt][r];

#pragma unroll
      for (int kc = 0; kc < 2; ++kc) {
        bf16x8 pf[2];
#pragma unroll
        for (int g = 0; g < 2; ++g)
          pf[g] = *(const bf16x8*)(&Ps[wave][(g * 16 + l15) * 72 + kc * 32 +
                                             quad * 8]);
#pragma unroll
        for (int mdt = 0; mdt < 4; ++mdt) {
          const int d = mdt * 16 + l15, sw = d & 7;
          bf16x8 vf =
              *(const bf16x8*)(Vs + d * 64 + (((kc * 4 + quad) ^ sw) * 8));
#pragma unroll
          for (int g = 0; g < 2; ++g)
            oacc[mdt][g] = __builtin_amdgcn_mfma_f32_16x16x32_bf16(
                vf, pf[g], oacc[mdt][g], 0, 0, 0);
        }
      }
    }

#pragma unroll
    for (int g = 0; g < 2; ++g)
#pragma unroll
      for (int r = 0; r < 4; ++r) {
        float s = lrun[g][r];
#pragma unroll
        for (int d = 1; d < 16; d <<= 1) s += __shfl_xor(s, d);
        if (l15 == 0) lL[wave * 32 + g * 16 + quad * 4 + r] = s;
      }
    float linv[2];
#pragma unroll
    for (int g = 0; g < 2; ++g) {
      const float l = lL[wave * 32 + g * 16 + l15];
      linv[g] = (qb + wave * 32 + g * 16 + l15 == 0) ? 0.0f : (1.0f / l);
    }
    __bf16* Ot = Ps[wave];
#pragma unroll
    for (int mdt = 0; mdt < 4; ++mdt)
#pragma unroll
      for (int g = 0; g < 2; ++g)
#pragma unroll
        for (int r = 0; r < 4; ++r)
          Ot[(g * 16 + l15) * 72 + mdt * 16 + quad * 4 + r] =
              (__bf16)(oacc[mdt][g][r] * linv[g]);
#pragma unroll
    for (int rr = 0; rr < 2; ++rr)
#pragma unroll
      for (int j = 0; j < 2; ++j) {
        const int row = rr * 16 + (lane >> 2), chk = (lane & 3) + 4 * j;
        bf16x8 ov = *(const bf16x8*)(Ot + row * 72 + chk * 8);
        const size_t oi = ((size_t)(b * 1024 + qb + wave * 32 + row)) * 1024 +
                          h * 64 + chk * 8;
        *(bf16x8*)(ctx + oi) = ov;
      }
  }
}

// ---------------------------------------------------------------------------
// out = LayerNorm(x + y) * g + beta ; rows of 1024, one block per row.
// ---------------------------------------------------------------------------
template <typename TX, typename TY, typename TO>
__global__ __launch_bounds__(256) void add_ln_kernel(const TX* __restrict__ x,
                                                     const TY* __restrict__ y,
                                                     const float* __restrict__ g,
                                                     const float* __restrict__ be,
                                                     TO* __restrict__ out) {
  const int row = blockIdx.x;
  const size_t base = (size_t)row * 1024;
  const int t = threadIdx.x;
  float xv[4], yv[4];
  if constexpr (sizeof(TX) == 4) {
    const float4 a = *(const float4*)(x + base + t * 4);
    xv[0] = a.x; xv[1] = a.y; xv[2] = a.z; xv[3] = a.w;
  } else {
    const bf16x4 a = *(const bf16x4*)(x + base + t * 4);
#pragma unroll
    for (int i = 0; i < 4; ++i) xv[i] = (float)a[i];
  }
  if constexpr (sizeof(TY) == 4) {
    const float4 a = *(const float4*)(y + base + t * 4);
    yv[0] = a.x; yv[1] = a.y; yv[2] = a.z; yv[3] = a.w;
  } else {
    const bf16x4 a = *(const bf16x4*)(y + base + t * 4);
#pragma unroll
    for (int i = 0; i < 4; ++i) yv[i] = (float)a[i];
  }
  float v[4], s = 0.0f, s2 = 0.0f;
#pragma unroll
  for (int i = 0; i < 4; ++i) {
    v[i] = xv[i] + yv[i];
    s += v[i];
    s2 += v[i] * v[i];
  }
#pragma unroll
  for (int m = 1; m < 64; m <<= 1) {
    s += __shfl_xor(s, m);
    s2 += __shfl_xor(s2, m);
  }
  __shared__ float ss[4], ss2[4];
  const int w = t >> 6;
  if ((t & 63) == 0) { ss[w] = s; ss2[w] = s2; }
  __syncthreads();
  s = ss[0] + ss[1] + ss[2] + ss[3];
  s2 = ss2[0] + ss2[1] + ss2[2] + ss2[3];
  const float mu = s * (1.0f / 1024.0f);
  const float var = s2 * (1.0f / 1024.0f) - mu * mu;
  const float rstd = rsqrtf(var + 1e-5f);
#pragma unroll
  for (int i = 0; i < 4; ++i) {
    const float o = (v[i] - mu) * rstd * g[t * 4 + i] + be[t * 4 + i];
    out[base + t * 4 + i] = (TO)o;
  }
}

// ---------------------------------------------------------------------------
extern "C" void kernel_launch(void* const* d_in, const int* in_sizes, int n_in,
                              void* d_out, int out_size, void* d_ws,
                              size_t ws_size, hipStream_t stream) {
  (void)in_sizes; (void)n_in; (void)out_size; (void)ws_size;
  const float* x   = (const float*)d_in[0];
  const float* Wq  = (const float*)d_in[1];
  const float* bq  = (const float*)d_in[2];
  const float* Wk  = (const float*)d_in[3];
  const float* bk  = (const float*)d_in[4];
  const float* Wv  = (const float*)d_in[5];
  const float* bv  = (const float*)d_in[6];
  const float* Wo  = (const float*)d_in[7];
  const float* bo  = (const float*)d_in[8];
  const float* W1  = (const float*)d_in[9];
  const float* b1  = (const float*)d_in[10];
  const float* W2  = (const float*)d_in[11];
  const float* b2  = (const float*)d_in[12];
  const float* g1  = (const float*)d_in[13];
  const float* be1 = (const float*)d_in[14];
  const float* g3  = (const float*)d_in[15];
  const float* be3 = (const float*)d_in[16];

  char* ws = (char*)d_ws;
  __bf16* Qb    = (__bf16*)(ws + 0);
  __bf16* Kb    = (__bf16*)(ws + (16u << 20));
  __bf16* Vb    = (__bf16*)(ws + (32u << 20));
  __bf16* ctx   = (__bf16*)(ws + (48u << 20));
  __bf16* mid   = (__bf16*)(ws + 0);
  __bf16* aout  = (__bf16*)(ws + (64u << 20));
  __bf16* h1    = aout;
  __bf16* xb    = (__bf16*)(ws + (80u << 20));
  __bf16* Vtb   = (__bf16*)(ws + (80u << 20));
  __bf16* fout  = (__bf16*)(ws + (80u << 20));
  __bf16* WqkvT = (__bf16*)(ws + (96u << 20));
  __bf16* WoT   = (__bf16*)(ws + (96u << 20) + 3 * (1u << 21));
  __bf16* W1T   = (__bf16*)(ws + (104u << 20));
  __bf16* W2T   = (__bf16*)(ws + (112u << 20));
  float*  bqkv  = (float*)(ws + (120u << 20));
  float*  outp  = (float*)d_out;

  const dim3 blk(256);
  // ---- prep
  convert_f2b_k<<<dim3(8192), blk, 0, stream>>>(x, xb);
  transpose4_f2b_k<<<dim3(32, 32, 4), blk, 0, stream>>>(Wq, Wk, Wv, Wo, WqkvT);
  transpose_f2b_k<<<dim3(128, 32), blk, 0, stream>>>(W1, W1T, 1024, 4096);
  transpose_f2b_k<<<dim3(32, 128), blk, 0, stream>>>(W2, W2T, 4096, 1024);
  concat3_k<<<dim3(12), blk, 0, stream>>>(bq, bk, bv, bqkv);

  // ---- QKV fused projection (head-split scatter)
  gemm_bt32<2><<<dim3(64, 24), blk, 0, stream>>>(xb, WqkvT, bqkv, Qb, 8192, 3072, 1024);
  // ---- V -> V^T per (b,h)
  transpose_v_k<<<dim3(32, 2, 128), blk, 0, stream>>>(Vb, Vtb);
  // ---- attention (balanced pairs, 4 waves/block — round-7 config)
  attn_kernel<<<dim3(4, 128), blk, 0, stream>>>(Qb, Kb, Vtb, ctx);
  // ---- output projection
  gemm_bt64<<<dim3(64, 16), blk, 0, stream>>>(ctx, WoT, bo, aout, 8192, 1024, 1024);
  // ---- h1 = LN(x + attn_out)
  add_ln_kernel<float, __bf16, __bf16><<<dim3(8192), blk, 0, stream>>>(
      x, aout, g1, be1, h1);
  // ---- FFN
  gemm_bt32<1><<<dim3(64, 32), blk, 0, stream>>>(h1, W1T, b1, mid, 8192, 4096, 1024);
  gemm_bt64<<<dim3(64, 16), blk, 0, stream>>>(mid, W2T, b2, fout, 8192, 1024, 4096);
  // ---- out = LN(h1 + ffn)
  add_ln_kernel<__bf16, __bf16, float><<<dim3(8192), blk, 0, stream>>>(
      h1, fout, g3, be3, outp);
}